// Round 12
// baseline (240.276 us; speedup 1.0000x reference)
//
#include <hip/hip_runtime.h>
#include <hip/hip_cooperative_groups.h>

namespace cg = cooperative_groups;

// Fused Damping v16: B=32768, N=64, H=256, OFF=2016.
// SINGLE cooperative kernel: 256 WGs x 1024 threads (1 WG/CU, co-resident),
// LDS 161,280 B. Phase 0: weight pack (4x256-thread sub-blocks per WG emulate
// the old 745 pack blocks; single uniform barrier; colmap inline). grid.sync().
// Then 4 rounds of the v15 fused body (32 batch rows each).
// Rationale: total-vs-fused gap grew to ~77us (~48% of total) = pack dispatch
// + 2nd launch + inter-dispatch gap. v13 proved the fused kernel's own stall
// is latency-structural; the gap is the last big target. Merging removes one
// dispatch and runs pack at 262k threads (~3us) + one grid barrier.
// v15 body unchanged: i8 P3/P4/P5, bf16 P2, MFMA OUT, VALU-diet tanh/q4i8.

#define BT 32
#define THREADS 1024
#define NWG 256

typedef short short8 __attribute__((ext_vector_type(8)));
typedef float floatx4 __attribute__((ext_vector_type(4)));
typedef float float2v __attribute__((ext_vector_type(2)));
typedef int   intx4  __attribute__((ext_vector_type(4)));

#define S_W    2032.0f           // Woo: 127/0.0625 ; xavier lim 0.0514
#define S_W2   1016.0f           // Wd2/Wo2: 127/0.125 ; lim 0.1082
#define S_WDO  812.8f            // Wdo: 127/0.15625 ; lim 0.1369
#define S_G    127.0f            // activations (tanh in (-1,1))
#define INV_SG (1.0f / (2032.0f * 127.0f))
#define INV_23 (1.0f / (1016.0f * 127.0f))
#define INV_DO (1.0f / (812.8f * 127.0f))

#if __has_builtin(__builtin_amdgcn_mfma_i32_16x16x64_i8)
#define MFMA_I8(acc, a, b) (acc) = __builtin_amdgcn_mfma_i32_16x16x64_i8((a), (b), (acc), 0, 0, 0)
#define MFMA_I8_FENCE()
#else
#define MFMA_I8(acc, a, b) asm("v_mfma_i32_16x16x64_i8 %0, %1, %2, %0" : "+v"(acc) : "v"(a), "v"(b))
#define MFMA_I8_FENCE() do { __builtin_amdgcn_sched_barrier(0); \
    asm volatile("s_nop 7\n\ts_nop 7\n\ts_nop 7"); } while (0)
#endif

__device__ __forceinline__ ushort f2bf(float f) {
    uint u = __builtin_bit_cast(uint, f);
    u += 0x7FFFu + ((u >> 16) & 1u);
    return (ushort)(u >> 16);
}
__device__ __forceinline__ uint cpk(float lo, float hi) {
    uint r;
    asm("v_cvt_pk_bf16_f32 %0, %1, %2" : "=v"(r) : "v"(lo), "v"(hi));
    return r;
}
__device__ __forceinline__ void pk_fma(float2v& d, float2v a, float2v b) {
    asm("v_pk_fma_f32 %0, %1, %2, %0" : "+v"(d) : "v"(a), "v"(b));
}
__device__ __forceinline__ float bf2f(ushort h) {
    return __builtin_bit_cast(float, ((uint)h) << 16);
}
__device__ __forceinline__ float bflo(uint u) { return __builtin_bit_cast(float, u << 16); }
__device__ __forceinline__ float bfhi(uint u) { return __builtin_bit_cast(float, u & 0xFFFF0000u); }

// tanh via single v_rcp_f32; rel err ~1e-7 << i8 grid.
__device__ __forceinline__ float fast_tanh(float x) {
    float y = __expf(2.f * x) + 1.f;
    float r;
    asm("v_rcp_f32 %0, %1" : "=v"(r) : "v"(y));
    return fmaf(-2.f, r, 1.f);
}
// magic-number i8 quantize (exact RNE for |g|<=1).
__device__ __forceinline__ uint q4i8(float g0, float g1, float g2, float g3) {
    uint b0 = __builtin_bit_cast(uint, fmaf(g0, S_G, 12582912.f));
    uint b1 = __builtin_bit_cast(uint, fmaf(g1, S_G, 12582912.f));
    uint b2 = __builtin_bit_cast(uint, fmaf(g2, S_G, 12582912.f));
    uint b3 = __builtin_bit_cast(uint, fmaf(g3, S_G, 12582912.f));
    return (b0 & 255u) | ((b1 & 255u) << 8) | ((b2 & 255u) << 16) | (b3 << 24);
}
__device__ __forceinline__ int s8idx(int k) {
    int a = k >> 3, r = k & 7;
    return 8 * (r ? (a + 1) * (4 * a + r - 1) : a * (4 * a + 3));
}
__device__ __forceinline__ int trik(int p) {
    int kr = (int)sqrtf(2.f * (float)p);
    if (kr < 1) kr = 1;
    if (kr > 63) kr = 63;
    while (kr < 63 && s8idx(kr + 1) <= p) kr++;
    while (kr > 1 && s8idx(kr) > p) kr--;
    return kr;
}

// ---- LDS layout (bytes), total 161,280 -> 1 WG/CU ----
#define BSTR8 2248
#define XBF_STR 88
#define A8STR 272
#define DGSTR 72
#define ACT_D8  8192
#define ACT_O8  16896
#define ACT_D28 25600
#define ACT_O28 34304
#define XS_B   143872
#define DG_B   152064
#define VB_B   156672
#define LDS_BYTES 161280

#define FRAGW(p, idx) (*(const short8*)((p) + (size_t)(idx) * 512 + (size_t)lane * 8))

#define LOADT(dst, t) do { \
    const intx4* fp_ = (const intx4*)(woo8 + (size_t)(t) * 4096 + (size_t)lane * 16); \
    _Pragma("unroll") \
    for (int kt_ = 0; kt_ < 4; kt_++) (dst)[kt_] = fp_[kt_ * 64]; \
} while (0)

#define COMPT(src, t) do { \
    intx4 alo_ = {0, 0, 0, 0}, ahi_ = {0, 0, 0, 0}; \
    _Pragma("unroll") \
    for (int kt_ = 0; kt_ < 4; kt_++) { \
        MFMA_I8(alo_, (src)[kt_], bfl8[kt_]); \
        MFMA_I8(ahi_, (src)[kt_], bfh8[kt_]); \
    } \
    MFMA_I8_FENCE(); \
    int p0_ = (t) * 16 + q * 4; \
    float4 bias_ = *(const float4*)(boo_p8 + p0_); \
    uint2 pw_; \
    pw_.x = cpk(fmaf((float)alo_[0], INV_SG, bias_.x), fmaf((float)alo_[1], INV_SG, bias_.y)); \
    pw_.y = cpk(fmaf((float)alo_[2], INV_SG, bias_.z), fmaf((float)alo_[3], INV_SG, bias_.w)); \
    *(uint2*)(off8 + ni * BSTR8 + p0_) = pw_; \
    pw_.x = cpk(fmaf((float)ahi_[0], INV_SG, bias_.x), fmaf((float)ahi_[1], INV_SG, bias_.y)); \
    pw_.y = cpk(fmaf((float)ahi_[2], INV_SG, bias_.z), fmaf((float)ahi_[3], INV_SG, bias_.w)); \
    *(uint2*)(off8 + (16 + ni) * BSTR8 + p0_) = pw_; \
} while (0)

__global__ __launch_bounds__(THREADS, 4)
void damping_all(const float* __restrict__ x,
                 const float* __restrict__ Wd1, const float* __restrict__ Wd2,
                 const float* __restrict__ Wdo, const float* __restrict__ Wo1,
                 const float* __restrict__ Wo2, const float* __restrict__ Woo,
                 const float* __restrict__ boo,
                 ushort* __restrict__ wd1f, ushort* __restrict__ wo1f,
                 unsigned char* __restrict__ wi8, float* __restrict__ boo_p8,
                 const float* __restrict__ bd1, const float* __restrict__ bd2,
                 const float* __restrict__ bdo, const float* __restrict__ bo1,
                 const float* __restrict__ bo2,
                 const float* __restrict__ dmin, float* __restrict__ out) {
    extern __shared__ char smem[];
    ushort* off8   = (ushort*)smem;
    ushort* xbf    = (ushort*)smem;
    unsigned char* act_d8  = (unsigned char*)(smem + ACT_D8);
    unsigned char* act_o8  = (unsigned char*)(smem + ACT_O8);
    unsigned char* act_d28 = (unsigned char*)(smem + ACT_D28);
    unsigned char* act_o28 = (unsigned char*)(smem + ACT_O28);
    float*  xs     = (float*)(smem + XS_B);
    ushort* dgb    = (ushort*)(smem + DG_B);
    ushort* vb     = (ushort*)(smem + VB_B);
    const unsigned char* wd28 = wi8;
    const unsigned char* wo28 = wi8 + 65536;
    const unsigned char* wdo8 = wi8 + 131072;
    const unsigned char* woo8 = wi8 + 147456;

    const int tid  = threadIdx.x;
    const int lane = tid & 63;
    const int w    = tid >> 6;          // 0..15
    const int q    = lane >> 4;
    const int ni   = lane & 15;

    // ================= PHASE 0: weight pack =================
    // 4 sub-blocks of 256 threads emulate old pack blocks 0..1023 (745 used).
    // Uniform structure: stage A (loads, colmap inline) -> 1 barrier -> stage B.
    {
        const int sb = tid >> 8, t2 = tid & 255;
        const int bid = blockIdx.x * 4 + sb;          // 0..1023
        // per-sub-block LDS scratch (2304 B each), overlays off8 (dead here)
        ushort* tr = (ushort*)smem + (size_t)sb * 1152;       // [64][18]
        signed char* tr8 = (signed char*)tr;                   // [64][20]

        const float* W = nullptr; unsigned char* dst = nullptr;
        int Ncols = 0, ntile = 0, segb = 0, woo = 0, i8p = 0, bf = 0;
        float scale = 0.f;
        int base_us = 0;
        if (bid < 16)       { W = Wd1; base_us = 0;     bf = 1; }
        else if (bid < 32)  { W = Wo1; base_us = 16384; bf = 1; }
        else if (bid < 96)  { W = Wd2; dst = wi8;          Ncols = 256;  ntile = 16;  segb = bid - 32;  scale = S_W2;  i8p = 1; }
        else if (bid < 160) { W = Wo2; dst = wi8 + 65536;  Ncols = 256;  ntile = 16;  segb = bid - 96;  scale = S_W2;  i8p = 1; }
        else if (bid < 176) { W = Wdo; dst = wi8 + 131072; Ncols = 64;   ntile = 4;   segb = bid - 160; scale = S_WDO; i8p = 1; }
        else if (bid < 736) { W = Woo; dst = wi8 + 147456; Ncols = 2016; ntile = 140; segb = bid - 176; scale = S_W;   i8p = 1; woo = 1; }
        const int kblk = i8p ? segb / ntile : 0;
        const int tile = i8p ? segb % ntile : (bf ? (bid & 15) : 0);

        // ---- stage A ----
        if (bid >= 736 && bid < 745) {
            int p = (bid - 736) * 256 + t2;
            if (p < 2240) {
                int kr = trik(p);
                int jj = p - s8idx(kr);
                boo_p8[p] = (jj < kr) ? boo[kr * (kr - 1) / 2 + jj] : 0.f;
            }
        } else if (i8p) {
            int r = t2 >> 2, c0q = (t2 & 3) * 4;
            const float* row = W + (size_t)(kblk * 64 + r) * Ncols;
#pragma unroll
            for (int i = 0; i < 4; i++) {
                int c = tile * 16 + c0q + i;
                float v;
                if (woo) {
                    int kr = trik(c);
                    int jj = c - s8idx(kr);
                    v = (jj < kr) ? row[kr * (kr - 1) / 2 + jj] : 0.f;
                } else {
                    v = row[c];
                }
                tr8[r * 20 + c0q + i] = (signed char)(int)__builtin_rintf(v * scale);
            }
        } else if (bf) {
            int r = t2 >> 2, c0q = (t2 & 3) * 4;
            const float* row = W + (size_t)r * 256 + tile * 16;
#pragma unroll
            for (int i = 0; i < 4; i++)
                tr[r * 18 + c0q + i] = f2bf(row[c0q + i]);
        }
        __syncthreads();
        // ---- stage B ----
        if (i8p) {
            int l = t2 >> 2, j0 = (t2 & 3) * 4;
            int qq = l >> 4, nn = l & 15;
            uint pk = 0;
#pragma unroll
            for (int i = 0; i < 4; i++) {
                int bb = (int)tr8[(qq * 16 + j0 + i) * 20 + nn];
                pk |= ((uint)bb & 255u) << (8 * i);
            }
            *(uint*)(dst + (size_t)tile * 4096 + kblk * 1024 + t2 * 4) = pk;
        } else if (bf) {
            ushort* wsb = (bid < 16) ? wd1f : wo1f;
            int e = t2 * 4;
            int ktl = e >> 9, rem = e & 511;
            int qq = rem >> 7, j0 = rem & 7;
            int nn = (rem >> 3) & 15;
            ushort v0 = tr[(ktl * 32 + qq * 8 + j0 + 0) * 18 + nn];
            ushort v1 = tr[(ktl * 32 + qq * 8 + j0 + 1) * 18 + nn];
            ushort v2 = tr[(ktl * 32 + qq * 8 + j0 + 2) * 18 + nn];
            ushort v3 = tr[(ktl * 32 + qq * 8 + j0 + 3) * 18 + nn];
            uint2 o;
            o.x = (uint)v0 | ((uint)v1 << 16);
            o.y = (uint)v2 | ((uint)v3 << 16);
            *(uint2*)(wsb + (size_t)(tile * 2 + ktl) * 512 + rem) = o;
        }
    }
    cg::this_grid().sync();

    // ================= PHASE 1..N: fused body x 4 rounds =================
    const int br = w >> 3;
    const int sp = w & 7;
    const int ts = (w + 12) & 15;
    const int nT = (ts < 12) ? 9 : 8;

    for (int round = 0; round < 4; ++round) {
        const int b0 = (blockIdx.x + round * NWG) * BT;

        // ---- P1: load x [32][64] fp32 + bf16 mirror ----
        if (tid < 512) {
            int row = tid >> 4;
            int c = (tid & 15) * 4;
            const float4 xv = *(const float4*)(x + (size_t)(b0 + row) * 64 + c);
            float* xr = xs + row * 64 + c;
            xr[0] = xv.x; xr[1] = xv.y; xr[2] = xv.z; xr[3] = xv.w;
            uint2 p;
            p.x = cpk(xv.x, xv.y);
            p.y = cpk(xv.z, xv.w);
            *(uint2*)(xbf + row * XBF_STR + c) = p;
        }
        __syncthreads();

        // ---- P2: layer1 (K=64, bf16 MFMA, bias in acc init), -> i8 acts ----
        {
            const ushort* wf = br ? wo1f : wd1f;
            const float*  bs = br ? bo1 : bd1;
            unsigned char* aout = br ? act_o8 : act_d8;
            float4 bias[2];
            floatx4 acc[2][2];
#pragma unroll
            for (int tt = 0; tt < 2; tt++) {
                bias[tt] = *(const float4*)(bs + (sp * 2 + tt) * 16 + q * 4);
                acc[tt][0] = (floatx4){bias[tt].x, bias[tt].y, bias[tt].z, bias[tt].w};
                acc[tt][1] = acc[tt][0];
            }
            for (int kt = 0; kt < 2; kt++) {
                short8 bl = *(const short8*)(xbf + ni * XBF_STR + kt * 32 + q * 8);
                short8 bh = *(const short8*)(xbf + (16 + ni) * XBF_STR + kt * 32 + q * 8);
#pragma unroll
                for (int tt = 0; tt < 2; tt++) {
                    short8 af = FRAGW(wf, (sp * 2 + tt) * 2 + kt);
                    acc[tt][0] = __builtin_amdgcn_mfma_f32_16x16x32_bf16(af, bl, acc[tt][0], 0, 0, 0);
                    acc[tt][1] = __builtin_amdgcn_mfma_f32_16x16x32_bf16(af, bh, acc[tt][1], 0, 0, 0);
                }
            }
#pragma unroll
            for (int tt = 0; tt < 2; tt++) {
                int col0 = (sp * 2 + tt) * 16 + q * 4;
#pragma unroll
                for (int hh = 0; hh < 2; hh++) {
                    uint pk = q4i8(fast_tanh(acc[tt][hh][0]),
                                   fast_tanh(acc[tt][hh][1]),
                                   fast_tanh(acc[tt][hh][2]),
                                   fast_tanh(acc[tt][hh][3]));
                    *(uint*)(aout + (hh * 16 + ni) * A8STR + col0) = pk;
                }
            }
        }
        __syncthreads();

        // ---- P3: layer2 (K=256, i8 MFMA) ----
        {
            const unsigned char* wf8 = br ? wo28 : wd28;
            const float* bs = br ? bo2 : bd2;
            const unsigned char* ain = br ? act_o8 : act_d8;
            unsigned char* aout = br ? act_o28 : act_d28;
            intx4 acc[2][2] = {};
            for (int kt = 0; kt < 4; kt++) {
                intx4 bl = *(const intx4*)(ain + ni * A8STR + kt * 64 + q * 16);
                intx4 bh = *(const intx4*)(ain + (16 + ni) * A8STR + kt * 64 + q * 16);
#pragma unroll
                for (int tt = 0; tt < 2; tt++) {
                    intx4 af = *(const intx4*)(wf8 + (size_t)(sp * 2 + tt) * 4096 + kt * 1024 + lane * 16);
                    MFMA_I8(acc[tt][0], af, bl);
                    MFMA_I8(acc[tt][1], af, bh);
                }
            }
            MFMA_I8_FENCE();
#pragma unroll
            for (int tt = 0; tt < 2; tt++) {
                int col0 = (sp * 2 + tt) * 16 + q * 4;
                float4 bias = *(const float4*)(bs + col0);
#pragma unroll
                for (int hh = 0; hh < 2; hh++) {
                    uint pk = q4i8(fast_tanh(fmaf((float)acc[tt][hh][0], INV_23, bias.x)),
                                   fast_tanh(fmaf((float)acc[tt][hh][1], INV_23, bias.y)),
                                   fast_tanh(fmaf((float)acc[tt][hh][2], INV_23, bias.z)),
                                   fast_tanh(fmaf((float)acc[tt][hh][3], INV_23, bias.w)));
                    *(uint*)(aout + (hh * 16 + ni) * A8STR + col0) = pk;
                }
            }
        }
        __syncthreads();

        // ---- P5 prep: preload i8 B-frags + first weight tile ----
        intx4 bfl8[4], bfh8[4];
#pragma unroll
        for (int kt = 0; kt < 4; kt++) {
            bfl8[kt] = *(const intx4*)(act_o28 + ni * A8STR + kt * 64 + q * 16);
            bfh8[kt] = *(const intx4*)(act_o28 + (16 + ni) * A8STR + kt * 64 + q * 16);
        }
        intx4 Af[4], Bf[4];
        LOADT(Af, ts);

        // ---- P4 (waves 0-3): diag layer3 (i8) ----
        if (w < 4) {
            intx4 acc[2] = {};
            for (int kt = 0; kt < 4; kt++) {
                intx4 bl = *(const intx4*)(act_d28 + ni * A8STR + kt * 64 + q * 16);
                intx4 bh = *(const intx4*)(act_d28 + (16 + ni) * A8STR + kt * 64 + q * 16);
                intx4 af = *(const intx4*)(wdo8 + (size_t)w * 4096 + kt * 1024 + lane * 16);
                MFMA_I8(acc[0], af, bl);
                MFMA_I8(acc[1], af, bh);
            }
            MFMA_I8_FENCE();
            int col0 = w * 16 + q * 4;
            float4 bias = *(const float4*)(bdo + col0);
            float4 dmv  = *(const float4*)(dmin + col0);
#pragma unroll
            for (int hh = 0; hh < 2; hh++) {
                int rB = hh * 16 + ni;
                float d, g0, g1, g2, g3;
                d = fmaf((float)acc[hh][0], INV_DO, bias.x); g0 = ((d > 0.f) ? d : 0.f) + dmv.x;
                d = fmaf((float)acc[hh][1], INV_DO, bias.y); g1 = ((d > 0.f) ? d : 0.f) + dmv.y;
                d = fmaf((float)acc[hh][2], INV_DO, bias.z); g2 = ((d > 0.f) ? d : 0.f) + dmv.z;
                d = fmaf((float)acc[hh][3], INV_DO, bias.w); g3 = ((d > 0.f) ? d : 0.f) + dmv.w;
                g0 *= xs[rB * 64 + col0];
                g1 *= xs[rB * 64 + col0 + 1];
                g2 *= xs[rB * 64 + col0 + 2];
                g3 *= xs[rB * 64 + col0 + 3];
                uint2 p;
                p.x = cpk(g0, g1);
                p.y = cpk(g2, g3);
                *(uint2*)(dgb + rB * DGSTR + col0) = p;
            }
        }
        __syncthreads();   // act reads done -> off8 free

        // ---- P5: i8 Woo GEMM ----
        {
            int tp = ts, it = 0;
            while (true) {
                bool more = (it + 1 < nT);
                if (more) LOADT(Bf, tp + 16);
                COMPT(Af, tp);
                ++it; tp += 16;
                if (!more) break;
                more = (it + 1 < nT);
                if (more) LOADT(Af, tp + 16);
                COMPT(Bf, tp);
                ++it; tp += 16;
                if (!more) break;
            }
        }
        __syncthreads();

        // ---- V ----
        const int ko = lane >> 3, jb = lane & 7;
        int toff[8];
#pragma unroll
        for (int kk = 0; kk < 8; kk++) toff[kk] = s8idx(kk * 8 + ko) + 8 * jb;
        const int bA = w * 2, bB = bA + 1;
        const ushort* rowA = off8 + bA * BSTR8;
        const ushort* rowB = rowA + BSTR8;
        {
            float2v sA0 = {0.f, 0.f}, sA1 = {0.f, 0.f}, sA2 = {0.f, 0.f}, sA3 = {0.f, 0.f};
            float2v sB0 = {0.f, 0.f}, sB1 = {0.f, 0.f}, sB2 = {0.f, 0.f}, sB3 = {0.f, 0.f};
#pragma unroll
            for (int kk = 0; kk < 8; kk++) {
                int k = kk * 8 + ko;
                uint4 uA = *(const uint4*)(rowA + toff[kk]);
                uint4 uB = *(const uint4*)(rowB + toff[kk]);
                float xkA = xs[bA * 64 + k];
                float xkB = xs[bB * 64 + k];
                bool live = (8 * jb < k);
                xkA = live ? xkA : 0.f;
                xkB = live ? xkB : 0.f;
                float2v xA2 = {xkA, xkA}, xB2 = {xkB, xkB};
                float2v p;
                p = (float2v){bflo(uA.x), bfhi(uA.x)}; pk_fma(sA0, p, xA2);
                p = (float2v){bflo(uB.x), bfhi(uB.x)}; pk_fma(sB0, p, xB2);
                p = (float2v){bflo(uA.y), bfhi(uA.y)}; pk_fma(sA1, p, xA2);
                p = (float2v){bflo(uB.y), bfhi(uB.y)}; pk_fma(sB1, p, xB2);
                p = (float2v){bflo(uA.z), bfhi(uA.z)}; pk_fma(sA2, p, xA2);
                p = (float2v){bflo(uB.z), bfhi(uB.z)}; pk_fma(sB2, p, xB2);
                p = (float2v){bflo(uA.w), bfhi(uA.w)}; pk_fma(sA3, p, xA2);
                p = (float2v){bflo(uB.w), bfhi(uB.w)}; pk_fma(sB3, p, xB2);
            }
            float s[16] = {sA0.x, sA0.y, sA1.x, sA1.y, sA2.x, sA2.y, sA3.x, sA3.y,
                           sB0.x, sB0.y, sB1.x, sB1.y, sB2.x, sB2.y, sB3.x, sB3.y};
#pragma unroll
            for (int e = 0; e < 16; e++) {
                s[e] += __shfl_xor(s[e], 8);
                s[e] += __shfl_xor(s[e], 16);
                s[e] += __shfl_xor(s[e], 32);
            }
            if (lane < 8) {               // ko==0, jb==lane
                int j0 = lane * 8;
#pragma unroll
                for (int r = 0; r < 2; r++) {
                    int b = bA + r;
                    float* sr = s + r * 8;
                    uint4 d = *(const uint4*)(dgb + b * DGSTR + j0);
                    float4 xa = *(const float4*)(xs + b * 64 + j0);
                    float4 xc = *(const float4*)(xs + b * 64 + j0 + 4);
                    sr[0] += bflo(d.x) * xa.x; sr[1] += bfhi(d.x) * xa.y;
                    sr[2] += bflo(d.y) * xa.z; sr[3] += bfhi(d.y) * xa.w;
                    sr[4] += bflo(d.z) * xc.x; sr[5] += bfhi(d.z) * xc.y;
                    sr[6] += bflo(d.w) * xc.z; sr[7] += bfhi(d.w) * xc.w;
                    uint4 o;
                    o.x = cpk(sr[0], sr[1]); o.y = cpk(sr[2], sr[3]);
                    o.z = cpk(sr[4], sr[5]); o.w = cpk(sr[6], sr[7]);
                    *(uint4*)(vb + b * DGSTR + j0) = o;
                }
            }
        }
        // NO barrier: OUT reads only own-wave vb/dgb rows + off8 (post-P5 bar).

        // ---- OUT via MFMA ----
        {
            const short8 z8 = {};
#pragma unroll
            for (int r = 0; r < 2; r++) {
                int b = bA + r;
                const ushort* rowt = off8 + b * BSTR8;
                const ushort* vrow = vb + b * DGSTR;
                short8 bv0 = *(const short8*)(vrow + q * 8);
                short8 bv1 = *(const short8*)(vrow + 32 + q * 8);
                bv0 = (ni == 0) ? bv0 : z8;
                bv1 = (ni == 0) ? bv1 : z8;
#pragma unroll
                for (int ib = 0; ib < 4; ib++) {
                    const int i0 = ib * 16;
                    const int soff = s8idx(i0 + ni);
                    floatx4 acc = {};
                    {
                        short8 a = *(const short8*)(rowt + soff + q * 8);
                        if (ib < 2) a = (q * 8 < i0 + ni) ? a : z8;
                        acc = __builtin_amdgcn_mfma_f32_16x16x32_bf16(a, bv0, acc, 0, 0, 0);
                    }
                    if (ib >= 2) {
                        short8 a = *(const short8*)(rowt + soff + 32 + q * 8);
                        a = (32 + q * 8 < i0 + ni) ? a : z8;
                        acc = __builtin_amdgcn_mfma_f32_16x16x32_bf16(a, bv1, acc, 0, 0, 0);
                    }
                    if (ni == 0) {
                        int i = i0 + q * 4;
                        uint2 d  = *(const uint2*)(dgb + b * DGSTR + i);
                        uint2 vv = *(const uint2*)(vb + b * DGSTR + i);
                        float4 o;
                        o.x = fmaf(bflo(d.x), bflo(vv.x), acc[0]);
                        o.y = fmaf(bfhi(d.x), bfhi(vv.x), acc[1]);
                        o.z = fmaf(bflo(d.y), bflo(vv.y), acc[2]);
                        o.w = fmaf(bfhi(d.y), bfhi(vv.y), acc[3]);
                        *(float4*)(out + (size_t)(b0 + b) * 64 + i) = o;
                    }
                }
            }
        }
        __syncthreads();   // off8/vb/dgb reads done before next round's writes
    }
}

extern "C" void kernel_launch(void* const* d_in, const int* in_sizes, int n_in,
                              void* d_out, int out_size, void* d_ws, size_t ws_size,
                              hipStream_t stream) {
    const float* x    = (const float*)d_in[0];
    const float* Wd1  = (const float*)d_in[1];
    const float* bd1  = (const float*)d_in[2];
    const float* Wd2  = (const float*)d_in[3];
    const float* bd2  = (const float*)d_in[4];
    const float* Wdo  = (const float*)d_in[5];
    const float* bdo  = (const float*)d_in[6];
    const float* Wo1  = (const float*)d_in[7];
    const float* bo1  = (const float*)d_in[8];
    const float* Wo2  = (const float*)d_in[9];
    const float* bo2  = (const float*)d_in[10];
    const float* Woo  = (const float*)d_in[11];
    const float* boo  = (const float*)d_in[12];
    const float* dmin = (const float*)d_in[13];
    float* out = (float*)d_out;

    // ws layout (bytes): wd1f@0 (32K), wo1f@32768 (32K), wi8@65536 (720K),
    // boo_p8 @ 1,507,328.
    ushort* wd1f = (ushort*)d_ws;
    ushort* wo1f = (ushort*)d_ws + 16384;
    unsigned char* wi8 = (unsigned char*)d_ws + 65536;
    float* boo_p8 = (float*)((unsigned char*)d_ws + 1507328);

    hipFuncSetAttribute((const void*)damping_all,
                        hipFuncAttributeMaxDynamicSharedMemorySize, LDS_BYTES);

    void* args[] = {
        (void*)&x, (void*)&Wd1, (void*)&Wd2, (void*)&Wdo, (void*)&Wo1,
        (void*)&Wo2, (void*)&Woo, (void*)&boo,
        (void*)&wd1f, (void*)&wo1f, (void*)&wi8, (void*)&boo_p8,
        (void*)&bd1, (void*)&bd2, (void*)&bdo, (void*)&bo1, (void*)&bo2,
        (void*)&dmin, (void*)&out
    };
    hipLaunchCooperativeKernel((void*)damping_all, dim3(NWG), dim3(THREADS),
                               args, LDS_BYTES, stream);
}

// Round 13
// 158.353 us; speedup vs baseline: 1.5173x; 1.5173x over previous
//
#include <hip/hip_runtime.h>

// Fused Damping v17 == v15 (REVERT of v16's cooperative merge).
// v16 findings: grid.sync() = device-scope fence -> L2 writeback+invalidate
// across 8 non-coherent XCDs -> FETCH 7.3->65MB, WRITE 8.2->58MB, kernel
// 135us; coop launch overhead > dual-dispatch (gap 77->105us). Gap is
// harness-fixed. Best config: BT=32, 1024 thr, 1 WG/CU, LDS 161,280 B.
// Pipeline: bf16 P2 (bias in acc), i8 P3/P4/P5 (builtin MFMA), MFMA OUT,
// VALU-diet (rcp-tanh, magic-number q4i8), pack_all4 separate dispatch.
// Measured (R11): 158.0us total, 81.4us fused, absmax 2.5.

#define BT 32
#define THREADS 1024

typedef short short8 __attribute__((ext_vector_type(8)));
typedef float floatx4 __attribute__((ext_vector_type(4)));
typedef float float2v __attribute__((ext_vector_type(2)));
typedef int   intx4  __attribute__((ext_vector_type(4)));

#define S_W    2032.0f           // Woo: 127/0.0625 ; xavier lim 0.0514
#define S_W2   1016.0f           // Wd2/Wo2: 127/0.125 ; lim 0.1082
#define S_WDO  812.8f            // Wdo: 127/0.15625 ; lim 0.1369
#define S_G    127.0f            // activations (tanh in (-1,1))
#define INV_SG (1.0f / (2032.0f * 127.0f))
#define INV_23 (1.0f / (1016.0f * 127.0f))
#define INV_DO (1.0f / (812.8f * 127.0f))

#if __has_builtin(__builtin_amdgcn_mfma_i32_16x16x64_i8)
#define MFMA_I8(acc, a, b) (acc) = __builtin_amdgcn_mfma_i32_16x16x64_i8((a), (b), (acc), 0, 0, 0)
#define MFMA_I8_FENCE()
#else
#define MFMA_I8(acc, a, b) asm("v_mfma_i32_16x16x64_i8 %0, %1, %2, %0" : "+v"(acc) : "v"(a), "v"(b))
#define MFMA_I8_FENCE() do { __builtin_amdgcn_sched_barrier(0); \
    asm volatile("s_nop 7\n\ts_nop 7\n\ts_nop 7"); } while (0)
#endif

__device__ __forceinline__ ushort f2bf(float f) {
    uint u = __builtin_bit_cast(uint, f);
    u += 0x7FFFu + ((u >> 16) & 1u);
    return (ushort)(u >> 16);
}
__device__ __forceinline__ uint cpk(float lo, float hi) {
    uint r;
    asm("v_cvt_pk_bf16_f32 %0, %1, %2" : "=v"(r) : "v"(lo), "v"(hi));
    return r;
}
__device__ __forceinline__ void pk_fma(float2v& d, float2v a, float2v b) {
    asm("v_pk_fma_f32 %0, %1, %2, %0" : "+v"(d) : "v"(a), "v"(b));
}
__device__ __forceinline__ float bf2f(ushort h) {
    return __builtin_bit_cast(float, ((uint)h) << 16);
}
__device__ __forceinline__ float bflo(uint u) { return __builtin_bit_cast(float, u << 16); }
__device__ __forceinline__ float bfhi(uint u) { return __builtin_bit_cast(float, u & 0xFFFF0000u); }

// tanh via single v_rcp_f32; rel err ~1e-7 << i8 grid.
__device__ __forceinline__ float fast_tanh(float x) {
    float y = __expf(2.f * x) + 1.f;
    float r;
    asm("v_rcp_f32 %0, %1" : "=v"(r) : "v"(y));
    return fmaf(-2.f, r, 1.f);
}
// magic-number i8 quantize (exact RNE for |g|<=1).
__device__ __forceinline__ uint q4i8(float g0, float g1, float g2, float g3) {
    uint b0 = __builtin_bit_cast(uint, fmaf(g0, S_G, 12582912.f));
    uint b1 = __builtin_bit_cast(uint, fmaf(g1, S_G, 12582912.f));
    uint b2 = __builtin_bit_cast(uint, fmaf(g2, S_G, 12582912.f));
    uint b3 = __builtin_bit_cast(uint, fmaf(g3, S_G, 12582912.f));
    return (b0 & 255u) | ((b1 & 255u) << 8) | ((b2 & 255u) << 16) | (b3 << 24);
}
__device__ __forceinline__ int s8idx(int k) {
    int a = k >> 3, r = k & 7;
    return 8 * (r ? (a + 1) * (4 * a + r - 1) : a * (4 * a + 3));
}
__device__ __forceinline__ int trik(int p) {
    int kr = (int)sqrtf(2.f * (float)p);
    if (kr < 1) kr = 1;
    if (kr > 63) kr = 63;
    while (kr < 63 && s8idx(kr + 1) <= p) kr++;
    while (kr > 1 && s8idx(kr) > p) kr--;
    return kr;
}

// ---- pack v4: bf16 layer1, i8 for the rest ----
__global__ __launch_bounds__(256)
void pack_all4(const float* __restrict__ Wd1, const float* __restrict__ Wd2,
               const float* __restrict__ Wdo, const float* __restrict__ Wo1,
               const float* __restrict__ Wo2, const float* __restrict__ Woo,
               const float* __restrict__ boo,
               ushort* __restrict__ ws, unsigned char* __restrict__ wi8,
               float* __restrict__ boo_p8) {
    const int bid = blockIdx.x, tid = threadIdx.x;
    if (bid >= 736) {
        int p = (bid - 736) * 256 + tid;
        if (p < 2240) {
            int kr = trik(p);
            int jj = p - s8idx(kr);
            boo_p8[p] = (jj < kr) ? boo[kr * (kr - 1) / 2 + jj] : 0.f;
        }
        return;
    }
    if (bid >= 32) {
        const float* W; unsigned char* dst; int Ncols, ntile, segb, woo = 0;
        float scale;
        if (bid < 96)       { W = Wd2; dst = wi8;          Ncols = 256;  ntile = 16;  segb = bid - 32;  scale = S_W2; }
        else if (bid < 160) { W = Wo2; dst = wi8 + 65536;  Ncols = 256;  ntile = 16;  segb = bid - 96;  scale = S_W2; }
        else if (bid < 176) { W = Wdo; dst = wi8 + 131072; Ncols = 64;   ntile = 4;   segb = bid - 160; scale = S_WDO; }
        else                { W = Woo; dst = wi8 + 147456; Ncols = 2016; ntile = 140; segb = bid - 176; scale = S_W; woo = 1; }
        int kblk = segb / ntile, tile = segb % ntile;
        __shared__ int colmap8[16];
        __shared__ signed char tr8[64][20];
        if (tid < 16) {
            int c = tile * 16 + tid;
            if (woo) {
                int kr = trik(c);
                int jj = c - s8idx(kr);
                c = (jj < kr) ? kr * (kr - 1) / 2 + jj : -1;
            }
            colmap8[tid] = c;
        }
        __syncthreads();
        {
            int r = tid >> 2, c0 = (tid & 3) * 4;
            const float* row = W + (size_t)(kblk * 64 + r) * Ncols;
#pragma unroll
            for (int i = 0; i < 4; i++) {
                int cm = colmap8[c0 + i];
                float v = (cm >= 0) ? row[cm] : 0.f;
                tr8[r][c0 + i] = (signed char)(int)__builtin_rintf(v * scale);
            }
        }
        __syncthreads();
        {
            int l = tid >> 2, j0 = (tid & 3) * 4;
            int q = l >> 4, ni = l & 15;
            uint pk = 0;
#pragma unroll
            for (int i = 0; i < 4; i++) {
                int b = (int)tr8[q * 16 + j0 + i][ni];
                pk |= ((uint)b & 255u) << (8 * i);
            }
            *(uint*)(dst + (size_t)tile * 4096 + kblk * 1024 + tid * 4) = pk;
        }
        return;
    }
    const float* W; int base_us, segb;
    if (bid < 16) { W = Wd1; base_us = 0;     segb = bid; }
    else          { W = Wo1; base_us = 16384; segb = bid - 16; }
    const int tile = segb;

    __shared__ ushort tr[64][18];
    {
        int r = tid >> 2, c0 = (tid & 3) * 4;
        const float* row = W + (size_t)r * 256 + tile * 16;
#pragma unroll
        for (int i = 0; i < 4; i++)
            tr[r][c0 + i] = f2bf(row[c0 + i]);
    }
    __syncthreads();
    {
        int e = tid * 4;
        int ktl = e >> 9, rem = e & 511;
        int q = rem >> 7, j0 = rem & 7;
        int ni = (rem >> 3) & 15;
        ushort v0 = tr[ktl * 32 + q * 8 + j0 + 0][ni];
        ushort v1 = tr[ktl * 32 + q * 8 + j0 + 1][ni];
        ushort v2 = tr[ktl * 32 + q * 8 + j0 + 2][ni];
        ushort v3 = tr[ktl * 32 + q * 8 + j0 + 3][ni];
        uint2 o;
        o.x = (uint)v0 | ((uint)v1 << 16);
        o.y = (uint)v2 | ((uint)v3 << 16);
        *(uint2*)(ws + (size_t)base_us + (size_t)(tile * 2 + ktl) * 512 + rem) = o;
    }
}

// ---- LDS layout (bytes), total 161,280 -> 1 WG/CU ----
#define BSTR8 2248
#define XBF_STR 88
#define A8STR 272
#define DGSTR 72
#define ACT_D8  8192
#define ACT_O8  16896
#define ACT_D28 25600
#define ACT_O28 34304
#define XS_B   143872
#define DG_B   152064
#define VB_B   156672
#define LDS_BYTES 161280

#define FRAGW(p, idx) (*(const short8*)((p) + (size_t)(idx) * 512 + (size_t)lane * 8))

#define LOADT(dst, t) do { \
    const intx4* fp_ = (const intx4*)(woo8 + (size_t)(t) * 4096 + (size_t)lane * 16); \
    _Pragma("unroll") \
    for (int kt_ = 0; kt_ < 4; kt_++) (dst)[kt_] = fp_[kt_ * 64]; \
} while (0)

#define COMPT(src, t) do { \
    intx4 alo_ = {0, 0, 0, 0}, ahi_ = {0, 0, 0, 0}; \
    _Pragma("unroll") \
    for (int kt_ = 0; kt_ < 4; kt_++) { \
        MFMA_I8(alo_, (src)[kt_], bfl8[kt_]); \
        MFMA_I8(ahi_, (src)[kt_], bfh8[kt_]); \
    } \
    MFMA_I8_FENCE(); \
    int p0_ = (t) * 16 + q * 4; \
    float4 bias_ = *(const float4*)(boo_p8 + p0_); \
    uint2 pw_; \
    pw_.x = cpk(fmaf((float)alo_[0], INV_SG, bias_.x), fmaf((float)alo_[1], INV_SG, bias_.y)); \
    pw_.y = cpk(fmaf((float)alo_[2], INV_SG, bias_.z), fmaf((float)alo_[3], INV_SG, bias_.w)); \
    *(uint2*)(off8 + ni * BSTR8 + p0_) = pw_; \
    pw_.x = cpk(fmaf((float)ahi_[0], INV_SG, bias_.x), fmaf((float)ahi_[1], INV_SG, bias_.y)); \
    pw_.y = cpk(fmaf((float)ahi_[2], INV_SG, bias_.z), fmaf((float)ahi_[3], INV_SG, bias_.w)); \
    *(uint2*)(off8 + (16 + ni) * BSTR8 + p0_) = pw_; \
} while (0)

__global__ __launch_bounds__(THREADS, 4)
void damping_fused(const float* __restrict__ x,
                   const ushort* __restrict__ wd1f, const ushort* __restrict__ wo1f,
                   const unsigned char* __restrict__ wd28,
                   const unsigned char* __restrict__ wo28,
                   const unsigned char* __restrict__ wdo8,
                   const unsigned char* __restrict__ woo8,
                   const float* __restrict__ bd1, const float* __restrict__ bd2,
                   const float* __restrict__ bdo, const float* __restrict__ bo1,
                   const float* __restrict__ bo2, const float* __restrict__ boo_p8,
                   const float* __restrict__ dmin, float* __restrict__ out) {
    extern __shared__ char smem[];
    ushort* off8   = (ushort*)smem;
    ushort* xbf    = (ushort*)smem;
    unsigned char* act_d8  = (unsigned char*)(smem + ACT_D8);
    unsigned char* act_o8  = (unsigned char*)(smem + ACT_O8);
    unsigned char* act_d28 = (unsigned char*)(smem + ACT_D28);
    unsigned char* act_o28 = (unsigned char*)(smem + ACT_O28);
    float*  xs     = (float*)(smem + XS_B);
    ushort* dgb    = (ushort*)(smem + DG_B);
    ushort* vb     = (ushort*)(smem + VB_B);

    const int tid  = threadIdx.x;
    const int lane = tid & 63;
    const int w    = tid >> 6;          // 0..15
    const int q    = lane >> 4;
    const int ni   = lane & 15;
    const int b0   = blockIdx.x * BT;

    // ---- P1: load x [32][64] fp32 + bf16 mirror ----
    if (tid < 512) {
        int row = tid >> 4;             // 0..31
        int c = (tid & 15) * 4;
        const float4 xv = *(const float4*)(x + (size_t)(b0 + row) * 64 + c);
        float* xr = xs + row * 64 + c;
        xr[0] = xv.x; xr[1] = xv.y; xr[2] = xv.z; xr[3] = xv.w;
        uint2 p;
        p.x = cpk(xv.x, xv.y);
        p.y = cpk(xv.z, xv.w);
        *(uint2*)(xbf + row * XBF_STR + c) = p;
    }
    __syncthreads();

    const int br = w >> 3;              // 0: diag branch (w 0-7), 1: off (w 8-15)
    const int sp = w & 7;               // col-strip pair: owns tiles sp*2, sp*2+1

    // ---- P2: layer1 (K=64, bf16 MFMA, bias in acc init), -> i8 acts ----
    {
        const ushort* wf = br ? wo1f : wd1f;
        const float*  bs = br ? bo1 : bd1;
        unsigned char* aout = br ? act_o8 : act_d8;
        float4 bias[2];
        floatx4 acc[2][2];              // [tt][half]
#pragma unroll
        for (int tt = 0; tt < 2; tt++) {
            bias[tt] = *(const float4*)(bs + (sp * 2 + tt) * 16 + q * 4);
            acc[tt][0] = (floatx4){bias[tt].x, bias[tt].y, bias[tt].z, bias[tt].w};
            acc[tt][1] = acc[tt][0];
        }
        for (int kt = 0; kt < 2; kt++) {
            short8 bl = *(const short8*)(xbf + ni * XBF_STR + kt * 32 + q * 8);
            short8 bh = *(const short8*)(xbf + (16 + ni) * XBF_STR + kt * 32 + q * 8);
#pragma unroll
            for (int tt = 0; tt < 2; tt++) {
                short8 af = FRAGW(wf, (sp * 2 + tt) * 2 + kt);
                acc[tt][0] = __builtin_amdgcn_mfma_f32_16x16x32_bf16(af, bl, acc[tt][0], 0, 0, 0);
                acc[tt][1] = __builtin_amdgcn_mfma_f32_16x16x32_bf16(af, bh, acc[tt][1], 0, 0, 0);
            }
        }
#pragma unroll
        for (int tt = 0; tt < 2; tt++) {
            int col0 = (sp * 2 + tt) * 16 + q * 4;
#pragma unroll
            for (int hh = 0; hh < 2; hh++) {
                uint pk = q4i8(fast_tanh(acc[tt][hh][0]),
                               fast_tanh(acc[tt][hh][1]),
                               fast_tanh(acc[tt][hh][2]),
                               fast_tanh(acc[tt][hh][3]));
                *(uint*)(aout + (hh * 16 + ni) * A8STR + col0) = pk;
            }
        }
    }
    __syncthreads();

    // ---- P3: layer2 (K=256, i8 MFMA), dedup'd: 2 col-tiles x both halves ----
    {
        const unsigned char* wf8 = br ? wo28 : wd28;
        const float* bs = br ? bo2 : bd2;
        const unsigned char* ain = br ? act_o8 : act_d8;
        unsigned char* aout = br ? act_o28 : act_d28;
        intx4 acc[2][2] = {};
        for (int kt = 0; kt < 4; kt++) {
            intx4 bl = *(const intx4*)(ain + ni * A8STR + kt * 64 + q * 16);
            intx4 bh = *(const intx4*)(ain + (16 + ni) * A8STR + kt * 64 + q * 16);
#pragma unroll
            for (int tt = 0; tt < 2; tt++) {
                intx4 af = *(const intx4*)(wf8 + (size_t)(sp * 2 + tt) * 4096 + kt * 1024 + lane * 16);
                MFMA_I8(acc[tt][0], af, bl);
                MFMA_I8(acc[tt][1], af, bh);
            }
        }
        MFMA_I8_FENCE();
#pragma unroll
        for (int tt = 0; tt < 2; tt++) {
            int col0 = (sp * 2 + tt) * 16 + q * 4;
            float4 bias = *(const float4*)(bs + col0);
#pragma unroll
            for (int hh = 0; hh < 2; hh++) {
                uint pk = q4i8(fast_tanh(fmaf((float)acc[tt][hh][0], INV_23, bias.x)),
                               fast_tanh(fmaf((float)acc[tt][hh][1], INV_23, bias.y)),
                               fast_tanh(fmaf((float)acc[tt][hh][2], INV_23, bias.z)),
                               fast_tanh(fmaf((float)acc[tt][hh][3], INV_23, bias.w)));
                *(uint*)(aout + (hh * 16 + ni) * A8STR + col0) = pk;
            }
        }
    }
    __syncthreads();

    // ---- P5 prep: preload i8 B-frags for BOTH row halves (32 VGPR) + first
    //      weight tile (hoisted so its L2 latency hides under P4) ----
    intx4 bfl8[4], bfh8[4];
#pragma unroll
    for (int kt = 0; kt < 4; kt++) {
        bfl8[kt] = *(const intx4*)(act_o28 + ni * A8STR + kt * 64 + q * 16);
        bfh8[kt] = *(const intx4*)(act_o28 + (16 + ni) * A8STR + kt * 64 + q * 16);
    }
    const int ts = (w + 12) & 15;       // waves 0-3 (P4 waves) get 8-tile slots
    const int nT = (ts < 12) ? 9 : 8;
    intx4 Af[4], Bf[4];
    LOADT(Af, ts);

    // ---- P4 (waves 0-3): diag layer3 (i8), 1 col-tile x both halves ----
    if (w < 4) {
        intx4 acc[2] = {};
        for (int kt = 0; kt < 4; kt++) {
            intx4 bl = *(const intx4*)(act_d28 + ni * A8STR + kt * 64 + q * 16);
            intx4 bh = *(const intx4*)(act_d28 + (16 + ni) * A8STR + kt * 64 + q * 16);
            intx4 af = *(const intx4*)(wdo8 + (size_t)w * 4096 + kt * 1024 + lane * 16);
            MFMA_I8(acc[0], af, bl);
            MFMA_I8(acc[1], af, bh);
        }
        MFMA_I8_FENCE();
        int col0 = w * 16 + q * 4;
        float4 bias = *(const float4*)(bdo + col0);
        float4 dmv  = *(const float4*)(dmin + col0);
#pragma unroll
        for (int hh = 0; hh < 2; hh++) {
            int rB = hh * 16 + ni;
            float d, g0, g1, g2, g3;
            d = fmaf((float)acc[hh][0], INV_DO, bias.x); g0 = ((d > 0.f) ? d : 0.f) + dmv.x;
            d = fmaf((float)acc[hh][1], INV_DO, bias.y); g1 = ((d > 0.f) ? d : 0.f) + dmv.y;
            d = fmaf((float)acc[hh][2], INV_DO, bias.z); g2 = ((d > 0.f) ? d : 0.f) + dmv.z;
            d = fmaf((float)acc[hh][3], INV_DO, bias.w); g3 = ((d > 0.f) ? d : 0.f) + dmv.w;
            g0 *= xs[rB * 64 + col0];
            g1 *= xs[rB * 64 + col0 + 1];
            g2 *= xs[rB * 64 + col0 + 2];
            g3 *= xs[rB * 64 + col0 + 3];
            uint2 p;
            p.x = cpk(g0, g1);
            p.y = cpk(g2, g3);
            *(uint2*)(dgb + rB * DGSTR + col0) = p;
        }
    }
    __syncthreads();   // all act/x reads of the overlay region done -> off8 free

    // ---- P5: i8 Woo GEMM, each A-frag load feeds 2 MFMAs (both halves) ----
    {
        int tp = ts, it = 0;
        while (true) {
            bool more = (it + 1 < nT);
            if (more) LOADT(Bf, tp + 16);
            COMPT(Af, tp);
            ++it; tp += 16;
            if (!more) break;
            more = (it + 1 < nT);
            if (more) LOADT(Af, tp + 16);
            COMPT(Bf, tp);
            ++it; tp += 16;
            if (!more) break;
        }
    }
    __syncthreads();

    // ---- precomputed triangle offsets for V ----
    const int ko = lane >> 3, jb = lane & 7;
    int toff[8];
#pragma unroll
    for (int kk = 0; kk < 8; kk++) toff[kk] = s8idx(kk * 8 + ko) + 8 * jb;
    const int bA = w * 2, bB = bA + 1;
    const ushort* rowA = off8 + bA * BSTR8;
    const ushort* rowB = rowA + BSTR8;

    // ---- V: v[j] = dg[j]*x[j] + sum_{k>j} off[k][j]*x[k], 2 rows interleaved ----
    {
        float2v sA0 = {0.f, 0.f}, sA1 = {0.f, 0.f}, sA2 = {0.f, 0.f}, sA3 = {0.f, 0.f};
        float2v sB0 = {0.f, 0.f}, sB1 = {0.f, 0.f}, sB2 = {0.f, 0.f}, sB3 = {0.f, 0.f};
#pragma unroll
        for (int kk = 0; kk < 8; kk++) {
            int k = kk * 8 + ko;
            uint4 uA = *(const uint4*)(rowA + toff[kk]);
            uint4 uB = *(const uint4*)(rowB + toff[kk]);
            float xkA = xs[bA * 64 + k];
            float xkB = xs[bB * 64 + k];
            bool live = (8 * jb < k);
            xkA = live ? xkA : 0.f;
            xkB = live ? xkB : 0.f;
            float2v xA2 = {xkA, xkA}, xB2 = {xkB, xkB};
            float2v p;
            p = (float2v){bflo(uA.x), bfhi(uA.x)}; pk_fma(sA0, p, xA2);
            p = (float2v){bflo(uB.x), bfhi(uB.x)}; pk_fma(sB0, p, xB2);
            p = (float2v){bflo(uA.y), bfhi(uA.y)}; pk_fma(sA1, p, xA2);
            p = (float2v){bflo(uB.y), bfhi(uB.y)}; pk_fma(sB1, p, xB2);
            p = (float2v){bflo(uA.z), bfhi(uA.z)}; pk_fma(sA2, p, xA2);
            p = (float2v){bflo(uB.z), bfhi(uB.z)}; pk_fma(sB2, p, xB2);
            p = (float2v){bflo(uA.w), bfhi(uA.w)}; pk_fma(sA3, p, xA2);
            p = (float2v){bflo(uB.w), bfhi(uB.w)}; pk_fma(sB3, p, xB2);
        }
        float s[16] = {sA0.x, sA0.y, sA1.x, sA1.y, sA2.x, sA2.y, sA3.x, sA3.y,
                       sB0.x, sB0.y, sB1.x, sB1.y, sB2.x, sB2.y, sB3.x, sB3.y};
#pragma unroll
        for (int e = 0; e < 16; e++) {
            s[e] += __shfl_xor(s[e], 8);
            s[e] += __shfl_xor(s[e], 16);
            s[e] += __shfl_xor(s[e], 32);
        }
        if (lane < 8) {               // ko==0, jb==lane
            int j0 = lane * 8;
#pragma unroll
            for (int r = 0; r < 2; r++) {
                int b = bA + r;
                float* sr = s + r * 8;
                uint4 d = *(const uint4*)(dgb + b * DGSTR + j0);
                float4 xa = *(const float4*)(xs + b * 64 + j0);
                float4 xc = *(const float4*)(xs + b * 64 + j0 + 4);
                sr[0] += bflo(d.x) * xa.x; sr[1] += bfhi(d.x) * xa.y;
                sr[2] += bflo(d.y) * xa.z; sr[3] += bfhi(d.y) * xa.w;
                sr[4] += bflo(d.z) * xc.x; sr[5] += bfhi(d.z) * xc.y;
                sr[6] += bflo(d.w) * xc.z; sr[7] += bfhi(d.w) * xc.w;
                uint4 o;
                o.x = cpk(sr[0], sr[1]); o.y = cpk(sr[2], sr[3]);
                o.z = cpk(sr[4], sr[5]); o.w = cpk(sr[6], sr[7]);
                *(uint4*)(vb + b * DGSTR + j0) = o;
            }
        }
    }
    // NO barrier: OUT reads only own-wave vb/dgb rows (same-wave DS ops are
    // program-ordered) + off8/dgb already covered by the post-P5 barrier.

    // ---- OUT via MFMA: out = L*v + diag ----
    {
        const short8 z8 = {};
#pragma unroll
        for (int r = 0; r < 2; r++) {
            int b = bA + r;
            const ushort* rowt = off8 + b * BSTR8;
            const ushort* vrow = vb + b * DGSTR;
            short8 bv0 = *(const short8*)(vrow + q * 8);
            short8 bv1 = *(const short8*)(vrow + 32 + q * 8);
            bv0 = (ni == 0) ? bv0 : z8;
            bv1 = (ni == 0) ? bv1 : z8;
#pragma unroll
            for (int ib = 0; ib < 4; ib++) {
                const int i0 = ib * 16;
                const int soff = s8idx(i0 + ni);
                floatx4 acc = {};
                {
                    short8 a = *(const short8*)(rowt + soff + q * 8);
                    if (ib < 2) a = (q * 8 < i0 + ni) ? a : z8;
                    acc = __builtin_amdgcn_mfma_f32_16x16x32_bf16(a, bv0, acc, 0, 0, 0);
                }
                if (ib >= 2) {
                    short8 a = *(const short8*)(rowt + soff + 32 + q * 8);
                    a = (32 + q * 8 < i0 + ni) ? a : z8;
                    acc = __builtin_amdgcn_mfma_f32_16x16x32_bf16(a, bv1, acc, 0, 0, 0);
                }
                if (ni == 0) {
                    int i = i0 + q * 4;
                    uint2 d  = *(const uint2*)(dgb + b * DGSTR + i);
                    uint2 vv = *(const uint2*)(vb + b * DGSTR + i);
                    float4 o;
                    o.x = fmaf(bflo(d.x), bflo(vv.x), acc[0]);
                    o.y = fmaf(bfhi(d.x), bfhi(vv.x), acc[1]);
                    o.z = fmaf(bflo(d.y), bflo(vv.y), acc[2]);
                    o.w = fmaf(bfhi(d.y), bfhi(vv.y), acc[3]);
                    *(float4*)(out + (size_t)(b0 + b) * 64 + i) = o;
                }
            }
        }
    }
}

extern "C" void kernel_launch(void* const* d_in, const int* in_sizes, int n_in,
                              void* d_out, int out_size, void* d_ws, size_t ws_size,
                              hipStream_t stream) {
    const float* x    = (const float*)d_in[0];
    const float* Wd1  = (const float*)d_in[1];
    const float* bd1  = (const float*)d_in[2];
    const float* Wd2  = (const float*)d_in[3];
    const float* bd2  = (const float*)d_in[4];
    const float* Wdo  = (const float*)d_in[5];
    const float* bdo  = (const float*)d_in[6];
    const float* Wo1  = (const float*)d_in[7];
    const float* bo1  = (const float*)d_in[8];
    const float* Wo2  = (const float*)d_in[9];
    const float* bo2  = (const float*)d_in[10];
    const float* Woo  = (const float*)d_in[11];
    const float* boo  = (const float*)d_in[12];
    const float* dmin = (const float*)d_in[13];
    float* out = (float*)d_out;

    // ws layout (bytes): bf16 layer1 frags [0, 65536): wd1f@0, wo1f@32768.
    // i8 region wi8 @ 65536: wd28 +0 (64K), wo28 +64K, wdo8 +128K (16K),
    // woo8 +144K (573,440) -> end 786,432. boo_p8 @ 1,507,328.
    ushort* ws   = (ushort*)d_ws;
    ushort* wd1f = ws;                      // [0, 16384) ushorts
    ushort* wo1f = ws + 16384;              // [16384, 32768) ushorts
    unsigned char* wi8  = (unsigned char*)d_ws + 65536;
    unsigned char* wd28 = wi8;
    unsigned char* wo28 = wi8 + 65536;
    unsigned char* wdo8 = wi8 + 131072;
    unsigned char* woo8 = wi8 + 147456;
    float*  boo_p8 = (float*)((unsigned char*)d_ws + 1507328);

    pack_all4<<<745, 256, 0, stream>>>(Wd1, Wd2, Wdo, Wo1, Wo2, Woo, boo,
                                       ws, wi8, boo_p8);

    hipFuncSetAttribute((const void*)damping_fused,
                        hipFuncAttributeMaxDynamicSharedMemorySize, LDS_BYTES);

    damping_fused<<<32768 / BT, THREADS, LDS_BYTES, stream>>>(
        x, wd1f, wo1f, wd28, wo28, wdo8, woo8,
        bd1, bd2, bdo, bo1, bo2, boo_p8, dmin, out);
}